// Round 5
// baseline (80.281 us; speedup 1.0000x reference)
//
#include <hip/hip_runtime.h>

typedef float f32x4 __attribute__((ext_vector_type(4)));
typedef __bf16 bf16x8 __attribute__((ext_vector_type(8)));
typedef __bf16 bf16x4 __attribute__((ext_vector_type(4)));

#define T_ 2048
#define DE 1024
#define DQ 64
#define SCALE 0.125f

// ---------- kernel 0: pack W (3x [1024][64] f32) into fragment-major bf16 Wf.
// Wf[(kc*12 + t)*64 + lane][8]: elem j = W[kc*32+(lane>>4)*8+j][(t&3)*16+(lane&15)],
// matrix = t>>2, kc = k/32.
__global__ __launch_bounds__(256) void kw_pack(
    const float* __restrict__ Wq, const float* __restrict__ Wk,
    const float* __restrict__ Wv, __bf16* __restrict__ Wf)
{
  int tid = blockIdx.x * 256 + threadIdx.x;   // 0..24575 = f*64 + lane
  int lane = tid & 63, f = tid >> 6;
  int t = f % 12, kc = f / 12;
  const float* W = (t < 4) ? Wq : ((t < 8) ? Wk : Wv);
  int nl = (t & 3) * 16 + (lane & 15);
  int k0 = kc * 32 + (lane >> 4) * 8;
  bf16x8 v;
#pragma unroll
  for (int j = 0; j < 8; ++j) v[j] = (__bf16)W[(size_t)(k0 + j) * 64 + nl];
  *(bf16x8*)(Wf + (size_t)tid * 8) = v;
}

// ---------- kernel 1: QKV projection. Block = 512 thr = 8 waves = (msub x kquarter).
// Reg-direct, ZERO barriers in k-loop; f32 LDS pairwise K-combine at the end.
__global__ __launch_bounds__(512, 4) void kproj(
    const float* __restrict__ x, const __bf16* __restrict__ Wf,
    __bf16* __restrict__ Qb, __bf16* __restrict__ Kb, __bf16* __restrict__ Vt)
{
  __shared__ float parts[2][2][12][256];      // 48 KB: [pair][msub][tile][lane*4+r]
  const int tid = threadIdx.x;
  const int lane = tid & 63;
  const int w = tid >> 6;                     // 0..7
  const int col = lane & 15, g = lane >> 4;
  const int msub = w & 1;                     // which 16-row half
  const int kq = w >> 1;                      // K quarter 0..3
  const int mbase = blockIdx.x * 32;

  f32x4 acc[12];
#pragma unroll
  for (int i = 0; i < 12; ++i) acc[i] = (f32x4){0.f, 0.f, 0.f, 0.f};

  // this lane's x row and K-quarter window
  const float* xr = x + (size_t)(mbase + msub * 16 + col) * DE + kq * 256 + g * 8;

#pragma unroll
  for (int ks = 0; ks < 8; ++ks) {
    f32x4 a0 = *(const f32x4*)(xr + ks * 32);
    f32x4 a1 = *(const f32x4*)(xr + ks * 32 + 4);
    bf16x8 af;
#pragma unroll
    for (int j = 0; j < 4; ++j) { af[j] = (__bf16)a0[j]; af[4 + j] = (__bf16)a1[j]; }
    const int kc = kq * 8 + ks;
    const __bf16* Wp = Wf + ((size_t)(kc * 12) * 64 + lane) * 8;
#pragma unroll
    for (int nt = 0; nt < 12; ++nt) {
      bf16x8 bfr = *(const bf16x8*)(Wp + (size_t)nt * 64 * 8);
      acc[nt] = __builtin_amdgcn_mfma_f32_16x16x32_bf16(af, bfr, acc[nt], 0, 0, 0);
    }
  }

  // pairwise K-combine in f32: kq1->kq0, kq3->kq2, then kq2->kq0
  if (kq & 1) {
    int p = kq >> 1;
#pragma unroll
    for (int i = 0; i < 12; ++i) *(f32x4*)&parts[p][msub][i][lane * 4] = acc[i];
  }
  __syncthreads();
  if (!(kq & 1)) {
    int p = kq >> 1;
#pragma unroll
    for (int i = 0; i < 12; ++i) acc[i] += *(const f32x4*)&parts[p][msub][i][lane * 4];
  }
  __syncthreads();
  if (kq == 2) {
#pragma unroll
    for (int i = 0; i < 12; ++i) *(f32x4*)&parts[0][msub][i][lane * 4] = acc[i];
  }
  __syncthreads();
  if (kq == 0) {
#pragma unroll
    for (int i = 0; i < 12; ++i) acc[i] += *(const f32x4*)&parts[0][msub][i][lane * 4];

    // epilogue: D layout row = g*4+r (within 16-row tile), col = ti*16 + col
    const int b = mbase >> 11;
    const int mrow = mbase + msub * 16 + g * 4;
    const int trow = (mbase & 2047) + msub * 16 + g * 4;
#pragma unroll
    for (int ti = 0; ti < 12; ++ti) {
      if (ti < 8) {
        __bf16* dst = (ti < 4) ? Qb : Kb;
        int c = (ti & 3) * 16 + col;
#pragma unroll
        for (int r = 0; r < 4; ++r)
          dst[(size_t)(mrow + r) * DQ + c] = (__bf16)acc[ti][r];
      } else {
        int d = (ti - 8) * 16 + col;
        bf16x4 v;
#pragma unroll
        for (int r = 0; r < 4; ++r) v[r] = (__bf16)acc[ti][r];
        *(bf16x4*)(Vt + ((size_t)(b * DQ + d)) * T_ + trow) = v;
      }
    }
  }
}

// ---------- kernel 2: causal flash attention. Block = 16 q-rows, 4 waves split KV (KVB=64).
__global__ __launch_bounds__(256, 4) void kattn(
    const __bf16* __restrict__ Qb, const __bf16* __restrict__ Kb,
    const __bf16* __restrict__ Vt, float* __restrict__ out)
{
  __shared__ float accs[4][16][68];           // 17.4 KB
  __shared__ float mls[4][2][16];             // 0.5 KB
  __shared__ __bf16 plds[4][16][72];          // 9.2 KB

  const int tid = threadIdx.x;
  const int lane = tid & 63;
  const int w = tid >> 6;
  const int col = lane & 15, g = lane >> 4;
  const int b = blockIdx.x & 7;
  const int jq = 127 - (blockIdx.x >> 3);     // heavy q-tiles first
  const int qbase = jq * 16;

  const __bf16* Qp = Qb + (size_t)(b * T_ + qbase + col) * DQ + g * 8;
  bf16x8 qa0 = *(const bf16x8*)(Qp);
  bf16x8 qa1 = *(const bf16x8*)(Qp + 32);

  const __bf16* Kbb = Kb + (size_t)b * T_ * DQ;
  const __bf16* Vbb = Vt + (size_t)b * DQ * T_;

  f32x4 acc[4];
#pragma unroll
  for (int dt = 0; dt < 4; ++dt) acc[dt] = (f32x4){0.f,0.f,0.f,0.f};
  float mrun[4], lsum[4];
#pragma unroll
  for (int r = 0; r < 4; ++r) { mrun[r] = -1e30f; lsum[r] = 0.f; }

  const int nb = (jq >> 2) + 1;               // 64-key blocks covering [0, qbase+16)
  for (int it = w; it < nb; it += 4) {
    const int nbase = it * 64;

    bf16x8 kf_[4][2];
#pragma unroll
    for (int nt = 0; nt < 4; ++nt) {
      const __bf16* Kp = Kbb + (size_t)(nbase + nt * 16 + col) * DQ + g * 8;
      kf_[nt][0] = *(const bf16x8*)(Kp);
      kf_[nt][1] = *(const bf16x8*)(Kp + 32);
    }

    f32x4 s[4];
#pragma unroll
    for (int nt = 0; nt < 4; ++nt) {
      f32x4 t = __builtin_amdgcn_mfma_f32_16x16x32_bf16(qa0, kf_[nt][0],
                                                        (f32x4){0.f,0.f,0.f,0.f}, 0, 0, 0);
      s[nt] = __builtin_amdgcn_mfma_f32_16x16x32_bf16(qa1, kf_[nt][1], t, 0, 0, 0);
    }

    bf16x8 vf[4][2];
#pragma unroll
    for (int dt = 0; dt < 4; ++dt) {
      const __bf16* Vp = Vbb + (size_t)(dt * 16 + col) * T_ + nbase + g * 8;
      vf[dt][0] = *(const bf16x8*)(Vp);
      vf[dt][1] = *(const bf16x8*)(Vp + 32);
    }

#pragma unroll
    for (int nt = 0; nt < 4; ++nt)
#pragma unroll
      for (int r = 0; r < 4; ++r) s[nt][r] *= SCALE;
    if (it == nb - 1) {
#pragma unroll
      for (int nt = 0; nt < 4; ++nt)
#pragma unroll
        for (int r = 0; r < 4; ++r)
          if (nbase + nt * 16 + col > qbase + g * 4 + r) s[nt][r] = -1e30f;
    }

    float mv[4];
#pragma unroll
    for (int r = 0; r < 4; ++r)
      mv[r] = fmaxf(fmaxf(s[0][r], s[1][r]), fmaxf(s[2][r], s[3][r]));
#pragma unroll
    for (int sh = 1; sh <= 8; sh <<= 1)
#pragma unroll
      for (int r = 0; r < 4; ++r) mv[r] = fmaxf(mv[r], __shfl_xor(mv[r], sh, 64));

#pragma unroll
    for (int r = 0; r < 4; ++r) {
      float mn = fmaxf(mrun[r], mv[r]);
      float rs = __expf(mrun[r] - mn);
      mrun[r] = mn;
      float ps = 0.f;
#pragma unroll
      for (int nt = 0; nt < 4; ++nt) {
        s[nt][r] = __expf(s[nt][r] - mn);
        ps += s[nt][r];
      }
      lsum[r] = lsum[r] * rs + ps;
#pragma unroll
      for (int dt = 0; dt < 4; ++dt) acc[dt][r] *= rs;
    }

#pragma unroll
    for (int nt = 0; nt < 4; ++nt)
#pragma unroll
      for (int r = 0; r < 4; ++r)
        plds[w][g * 4 + r][nt * 16 + col] = (__bf16)s[nt][r];

    bf16x8 pa0 = *(const bf16x8*)&plds[w][col][g * 8];
    bf16x8 pa1 = *(const bf16x8*)&plds[w][col][32 + g * 8];

#pragma unroll
    for (int dt = 0; dt < 4; ++dt) {
      f32x4 t = __builtin_amdgcn_mfma_f32_16x16x32_bf16(pa0, vf[dt][0], acc[dt], 0, 0, 0);
      acc[dt] = __builtin_amdgcn_mfma_f32_16x16x32_bf16(pa1, vf[dt][1], t, 0, 0, 0);
    }
  }

#pragma unroll
  for (int sh = 1; sh <= 8; sh <<= 1)
#pragma unroll
    for (int r = 0; r < 4; ++r) lsum[r] += __shfl_xor(lsum[r], sh, 64);

#pragma unroll
  for (int r = 0; r < 4; ++r) {
    int row = g * 4 + r;
    accs[w][row][col]      = acc[0][r];
    accs[w][row][col + 16] = acc[1][r];
    accs[w][row][col + 32] = acc[2][r];
    accs[w][row][col + 48] = acc[3][r];
    if (col == 0) { mls[w][0][row] = mrun[r]; mls[w][1][row] = lsum[r]; }
  }
  __syncthreads();

  {
    int row = tid >> 4;                       // 0..15
    int c4 = (tid & 15) * 4;
    float m0 = mls[0][0][row], m1 = mls[1][0][row];
    float m2 = mls[2][0][row], m3 = mls[3][0][row];
    float M = fmaxf(fmaxf(m0, m1), fmaxf(m2, m3));
    float s0 = __expf(m0 - M), s1 = __expf(m1 - M);
    float s2 = __expf(m2 - M), s3 = __expf(m3 - M);
    float L = s0 * mls[0][1][row] + s1 * mls[1][1][row]
            + s2 * mls[2][1][row] + s3 * mls[3][1][row];
    f32x4 a0 = *(const f32x4*)&accs[0][row][c4];
    f32x4 a1 = *(const f32x4*)&accs[1][row][c4];
    f32x4 a2 = *(const f32x4*)&accs[2][row][c4];
    f32x4 a3 = *(const f32x4*)&accs[3][row][c4];
    float inv = 1.f / L;
    f32x4 o;
#pragma unroll
    for (int j = 0; j < 4; ++j)
      o[j] = (s0 * a0[j] + s1 * a1[j] + s2 * a2[j] + s3 * a3[j]) * inv;
    *(f32x4*)(out + (size_t)(b * T_ + qbase + row) * DQ + c4) = o;
  }
}

extern "C" void kernel_launch(void* const* d_in, const int* in_sizes, int n_in,
                              void* d_out, int out_size, void* d_ws, size_t ws_size,
                              hipStream_t stream)
{
  const float* x  = (const float*)d_in[0];
  const float* Wq = (const float*)d_in[1];
  const float* Wk = (const float*)d_in[2];
  const float* Wv = (const float*)d_in[3];
  float* out = (float*)d_out;

  char* ws = (char*)d_ws;
  __bf16* Wf = (__bf16*)(ws);                                   // 384 KiB
  __bf16* Qb = (__bf16*)(ws + 0x80000);                         // 2 MiB
  __bf16* Kb = (__bf16*)(ws + 0x80000 + 0x200000);              // 2 MiB
  __bf16* Vt = (__bf16*)(ws + 0x80000 + 0x400000);              // 2 MiB

  kw_pack<<<96, 256, 0, stream>>>(Wq, Wk, Wv, Wf);
  kproj<<<512, 512, 0, stream>>>(x, Wf, Qb, Kb, Vt);
  kattn<<<1024, 256, 0, stream>>>(Qb, Kb, Vt, out);
}